// Round 13
// baseline (34.087 us; speedup 1.0000x reference)
//
#include <hip/hip_runtime.h>

#define NN 177
#define NEG 0.2f
#define QR 45                 // dst rows per quarter (last quarter 42)
#define ROWP 180              // padded W row stride (16B-aligned)
#define QSLOTS_P (QR * ROWP)  // 8100
#define SL 8192               // partial slice stride (floats)
#define NCHUNK 64
#define EBLOCKS (NCHUNK * 4)  // 256
#define ETH 512

// workspace layout (floats)
#define H_OFF    768          // h[177][128]
#define PART_OFF 23424        // 256 slices of SL (~8.4 MB)

__device__ __forceinline__ float4 f4add(float4 a, float4 b) {
    return make_float4(a.x + b.x, a.y + b.y, a.z + b.z, a.w + b.w);
}

// K_A: fully self-sufficient edge pass (2-dispatch design).
//  preamble (replicated per block, parallel+coalesced):
//   u=W@att0, v=W@att1 (float4+shuffle); ai[n]=x[n]·u, aj[n]=x[n]·v via
//   x-layout-ordered float4s + aligned 32-lane group reduce (no atomics).
//  blocks 0..176 also write h row (for K_B). Then quarter edge pass (R12).
__global__ __launch_bounds__(ETH)
void k_edgeA(const float* __restrict__ x, const float* __restrict__ ea,
             const float* __restrict__ w, const float* __restrict__ att,
             const int* __restrict__ ei, float* __restrict__ ws, int E, int CH) {
    __shared__ __align__(16) float Wl[QSLOTS_P];
    __shared__ float ajl[NN], ail[NN], Mq[QR], llast[QR], mred[64];
    __shared__ float uvec[128], vvec[128], atl[257], xl[128];
    const int tid = threadIdx.x;
    const int bid = blockIdx.x;
    const int chunk = bid & (NCHUNK - 1), q = bid >> 6;   // XCD-swizzled
    const int dlo = q * QR;
    int drows = NN - dlo; if (drows > QR) drows = QR;

    for (int i = tid; i < 257; i += ETH) atl[i] = att[i];
    if (bid < NN && tid < 128) xl[tid] = x[bid * 128 + tid];
    __syncthreads();

    // ---- u, v (coalesced float4 + 32-lane shuffle; one writer per k) ----
    const float4* w4 = (const float4*)w;
#pragma unroll
    for (int i = 0; i < 8; ++i) {
        int f = i * 512 + tid;
        int k = f >> 5, c4 = (f & 31) << 2;
        float4 wv = w4[f];
        float pu = wv.x*atl[c4]     + wv.y*atl[c4+1]     + wv.z*atl[c4+2]     + wv.w*atl[c4+3];
        float pv = wv.x*atl[128+c4] + wv.y*atl[128+c4+1] + wv.z*atl[128+c4+2] + wv.w*atl[128+c4+3];
#pragma unroll
        for (int m = 1; m <= 16; m <<= 1) { pu += __shfl_xor(pu, m); pv += __shfl_xor(pv, m); }
        if ((tid & 31) == 0) { uvec[k] = pu; vvec[k] = pv; }
    }
    __syncthreads();

    // ---- ai[n]=x[n]·u, aj[n]=x[n]·v: x-natural-layout float4s, aligned
    //      32-lane group == one row n; 5-level shuffle; one writer per n ----
    const float4* x4p = (const float4*)x;
#pragma unroll
    for (int i = 0; i < 12; ++i) {
        int f = i * 512 + tid;
        bool valid = f < NN * 32;                 // 5664 float4s
        float4 xv = valid ? x4p[f] : make_float4(0.f, 0.f, 0.f, 0.f);
        int c4 = (f & 31) << 2;
        float pa = xv.x*uvec[c4] + xv.y*uvec[c4+1] + xv.z*uvec[c4+2] + xv.w*uvec[c4+3];
        float pb = xv.x*vvec[c4] + xv.y*vvec[c4+1] + xv.z*vvec[c4+2] + xv.w*vvec[c4+3];
#pragma unroll
        for (int m = 1; m <= 16; m <<= 1) { pa += __shfl_xor(pa, m); pb += __shfl_xor(pb, m); }
        if (valid && (tid & 31) == 0) { int n = f >> 5; ail[n] = pa; ajl[n] = pb; }
    }
    __syncthreads();

    // ---- parallel ajmax ----
    if (tid < 64) {
        float m = -1e30f;
        for (int i = tid; i < NN; i += 64) m = fmaxf(m, ajl[i]);
        mred[tid] = m;
    }
    __syncthreads();
    if (tid < 16) mred[tid] = fmaxf(fmaxf(mred[tid], mred[tid + 16]),
                                    fmaxf(mred[tid + 32], mred[tid + 48]));
    __syncthreads();
    if (tid < 4) mred[tid] = fmaxf(fmaxf(mred[tid], mred[tid + 4]),
                                   fmaxf(mred[tid + 8], mred[tid + 12]));
    __syncthreads();
    if (tid == 0) mred[0] = fmaxf(fmaxf(mred[0], mred[1]), fmaxf(mred[2], mred[3]));
    __syncthreads();
    const float ajmax = mred[0];

    // ---- blocks 0..176: h row (4-way split-K, Wl as scratch pre-zero) ----
    if (bid < NN) {
        const int c = tid & 127, kq = tid >> 7;
        const float* wp = w + (size_t)(kq * 32) * 128 + c;
        float a = 0.f;
#pragma unroll 8
        for (int k = 0; k < 32; ++k) a += xl[kq * 32 + k] * wp[(size_t)k * 128];
        Wl[tid] = a;
        __syncthreads();
        if (tid < 128)
            ws[H_OFF + bid * 128 + tid] = (Wl[tid] + Wl[128 + tid]) + (Wl[256 + tid] + Wl[384 + tid]);
        __syncthreads();
    }

    // ---- edge phase setup ----
    const float4 z4 = make_float4(0.f, 0.f, 0.f, 0.f);
    for (int i = tid; i < QSLOTS_P / 4; i += ETH) ((float4*)Wl)[i] = z4;
    if (tid < QR) llast[tid] = 0.f;
    if (tid < drows) {
        float M = ail[dlo + tid] + ajmax + 1.0f;   // safe softmax shift (shift-invariant)
        Mq[tid] = (M > 0.f) ? M : NEG * M;
    }
    const float cc = atl[256];
    __syncthreads();

    // ---- edge loop ----
    const int base = chunk * CH;
    int lim = base + CH; if (lim > E) lim = E;
    const bool aligned4 = ((E & 3) == 0);
    for (int e0 = base + tid * 4; e0 < lim; e0 += ETH * 4) {
        int4 sv, dv; float4 eav;
        if (aligned4 && e0 + 3 < lim) {
            sv  = *(const int4*)(ei + e0);
            dv  = *(const int4*)(ei + E + e0);
            eav = *(const float4*)(ea + e0);
        } else {
            int e1 = lim - e0;
            sv.x = (e1 > 0) ? ei[e0]     : 0; dv.x = (e1 > 0) ? ei[E + e0]     : -1; eav.x = (e1 > 0) ? ea[e0]     : 0.f;
            sv.y = (e1 > 1) ? ei[e0 + 1] : 0; dv.y = (e1 > 1) ? ei[E + e0 + 1] : -1; eav.y = (e1 > 1) ? ea[e0 + 1] : 0.f;
            sv.z = (e1 > 2) ? ei[e0 + 2] : 0; dv.z = (e1 > 2) ? ei[E + e0 + 2] : -1; eav.z = (e1 > 2) ? ea[e0 + 2] : 0.f;
            sv.w = (e1 > 3) ? ei[e0 + 3] : 0; dv.w = (e1 > 3) ? ei[E + e0 + 3] : -1; eav.w = (e1 > 3) ? ea[e0 + 3] : 0.f;
        }
#define PROC(SS, DD, EE) do {                                   \
            int d_ = (DD) - dlo;                                \
            if ((unsigned)d_ < (unsigned)drows) {               \
                float t_ = ail[dlo + d_] + ajl[SS] + cc * (EE); \
                t_ = (t_ > 0.f) ? t_ : NEG * t_;                \
                float ev_ = __expf(t_ - Mq[d_]);                \
                atomicAdd(&Wl[d_ * ROWP + (SS)], ev_);          \
                atomicAdd(&llast[d_], ev_ * (EE));              \
            }                                                   \
        } while (0)
        PROC(sv.x, dv.x, eav.x);
        PROC(sv.y, dv.y, eav.y);
        PROC(sv.z, dv.z, eav.z);
        PROC(sv.w, dv.w, eav.w);
#undef PROC
    }
    __syncthreads();
    float* part = ws + PART_OFF + (size_t)bid * SL;
    for (int i = tid; i < QSLOTS_P / 4; i += ETH)
        ((float4*)part)[i] = ((const float4*)Wl)[i];
    if (tid < QR) part[QSLOTS_P + tid] = llast[tid];
}

// K_B: float4 chunk-reduce (8-way) + 4-way-split v = W[n,:]@h + out = v@eu.
__global__ __launch_bounds__(ETH)
void k_outC(const float* __restrict__ ws, const float* __restrict__ eu,
            const float* __restrict__ bias, float* __restrict__ out) {
    __shared__ __align__(16) float wl[ROWP];
    __shared__ float vl[128];
    __shared__ float red[128];
    __shared__ float sc[2];
    __shared__ __align__(16) float hl[89 * 128];
    __shared__ __align__(16) float pd[2048];
    const int n = blockIdx.x, tid = threadIdx.x;
    const int q = n / QR, r = n % QR;
    const size_t qbase = PART_OFF + (size_t)q * NCHUNK * SL;

    {
        const int lane = tid & 63, cg = tid >> 6;
        const int s4 = lane * 4;
        float4 acc = make_float4(0.f, 0.f, 0.f, 0.f);
        if (s4 < ROWP) {
            const float* p = ws + qbase + (size_t)(cg * 8) * SL + (size_t)r * ROWP + s4;
#pragma unroll
            for (int ch = 0; ch < 8; ++ch)
                acc = f4add(acc, *(const float4*)(p + (size_t)ch * SL));
        }
        ((float4*)pd)[tid] = acc;
    }
    if (tid < 64) red[tid] = ws[qbase + (size_t)tid * SL + QSLOTS_P + r];
    __syncthreads();
    if (tid < 256) ((float4*)pd)[tid] = f4add(((float4*)pd)[tid], ((float4*)pd)[tid + 256]);
    if (tid < 32) red[tid] += red[tid + 32];
    __syncthreads();
    if (tid < 128) ((float4*)pd)[tid] = f4add(((float4*)pd)[tid], ((float4*)pd)[tid + 128]);
    if (tid < 16) red[tid] += red[tid + 16];
    __syncthreads();
    if (tid < 64) {
        float4 v = f4add(((float4*)pd)[tid], ((float4*)pd)[tid + 64]);
        if (tid * 4 < ROWP) ((float4*)wl)[tid] = v;
    }
    if (tid < 8) red[tid] += red[tid + 8];
    __syncthreads();
    if (tid == 0) {
        float wv = 0.f;
#pragma unroll
        for (int i = 0; i < 8; ++i) wv += red[i];
        sc[0] = wv;                                  // wlast_n
    }
    __syncthreads();
    if (tid < 128) red[tid] = wl[tid] + ((tid + 128 < NN) ? wl[tid + 128] : 0.f);
    __syncthreads();
    for (int off = 64; off > 0; off >>= 1) {
        if (tid < off) red[tid] += red[tid + off];
        __syncthreads();
    }
    if (tid == 0) sc[1] = red[0];

    const int c = tid & 127, g = tid >> 7;
    float vacc = 0.f;
    __syncthreads();
    for (int i = tid; i < 89 * 32; i += ETH)
        ((float4*)hl)[i] = ((const float4*)(ws + H_OFF))[i];
    __syncthreads();
    {
        int s0 = (g * 89) >> 2, s1 = ((g + 1) * 89) >> 2;
        for (int s = s0; s < s1; ++s) vacc += wl[s] * hl[s * 128 + c];
    }
    __syncthreads();
    for (int i = tid; i < 88 * 32; i += ETH)
        ((float4*)hl)[i] = ((const float4*)(ws + H_OFF + 89 * 128))[i];
    __syncthreads();
    {
        int s0 = (g * 88) >> 2, s1 = ((g + 1) * 88) >> 2;
        for (int s = s0; s < s1; ++s) vacc += wl[89 + s] * hl[s * 128 + c];
    }
    pd[tid] = vacc;
    __syncthreads();
    if (tid < 128) vl[tid] = (pd[tid] + pd[128 + tid]) + (pd[256 + tid] + pd[384 + tid]);
    __syncthreads();

    {
        const int kg = tid >> 7;
        float oacc = 0.f;
        const float* ep = eu + (size_t)(kg * 32) * 128 + c;
#pragma unroll 8
        for (int k = 0; k < 32; ++k) oacc += vl[kg * 32 + k] * ep[(size_t)k * 128];
        pd[tid] = oacc;
    }
    __syncthreads();
    if (tid < 128) {
        float dot = (pd[tid] + pd[128 + tid]) + (pd[256 + tid] + pd[384 + tid]);
        out[n * 128 + tid] = (dot + sc[0] * eu[128 * 128 + tid]) / (sc[1] + 1e-16f) + bias[tid];
    }
}

extern "C" void kernel_launch(void* const* d_in, const int* in_sizes, int n_in,
                              void* d_out, int out_size, void* d_ws, size_t ws_size,
                              hipStream_t stream) {
    const float* x     = (const float*)d_in[0];
    const float* eattr = (const float*)d_in[1];
    const float* w     = (const float*)d_in[2];
    const float* att   = (const float*)d_in[3];
    const float* eu    = (const float*)d_in[4];
    const float* bias  = (const float*)d_in[5];
    const int*   ei    = (const int*)d_in[6];
    int E = in_sizes[6] / 2;
    int CH = (((E + NCHUNK - 1) / NCHUNK) + 3) & ~3;
    float* ws = (float*)d_ws;

    k_edgeA<<<EBLOCKS, ETH, 0, stream>>>(x, eattr, w, att, ei, ws, E, CH);
    k_outC<<<NN, ETH, 0, stream>>>(ws, eu, bias, (float*)d_out);
}

// Round 14
// 31.780 us; speedup vs baseline: 1.0726x; 1.0726x over previous
//
#include <hip/hip_runtime.h>

#define NN 177
#define NEG 0.2f
#define QR 45                 // dst rows per quarter (last quarter 42)
#define ROWP 180              // padded W row stride (16B-aligned)
#define QSLOTS_P (QR * ROWP)  // 8100
#define SL 8192               // partial slice stride (floats)
#define NCHUNK 64
#define EBLOCKS (NCHUNK * 4)  // 256
#define ETH 512

// workspace layout (floats)
#define AIP_OFF  0            // 354 per-(n,half) ai partials
#define AJP_OFF  384
#define PART_OFF 768          // 256 slices of SL (~8.4 MB), 16B aligned

__device__ __forceinline__ float4 f4add(float4 a, float4 b) {
    return make_float4(a.x + b.x, a.y + b.y, a.z + b.z, a.w + b.w);
}

// K1: ai/aj partial dots only (h never materialized — factorized into K3).
// Grid (177, 2): block = (row n, col half). 4-way split-K.
__global__ __launch_bounds__(256)
void k_nodeA(const float* __restrict__ x, const float* __restrict__ w,
             const float* __restrict__ att, float* __restrict__ ws) {
    const int n = blockIdx.x, half = blockIdx.y;
    const int tid = threadIdx.x;
    const int j = tid & 63, kq = tid >> 6;
    __shared__ float xl[128];
    __shared__ float ph[256];
    if (tid < 128) xl[tid] = x[n * 128 + tid];
    __syncthreads();
    const float* wp = w + (size_t)(kq * 32) * 128 + half * 64 + j;
    float acc = 0.f;
#pragma unroll 8
    for (int k = 0; k < 32; ++k) acc += xl[kq * 32 + k] * wp[(size_t)k * 128];
    ph[tid] = acc;
    __syncthreads();
    if (tid < 64) {
        float hv = ph[j] + ph[64 + j] + ph[128 + j] + ph[192 + j];
        float pa = hv * att[half * 64 + j];
        float pb = hv * att[128 + half * 64 + j];
#pragma unroll
        for (int m = 1; m < 64; m <<= 1) {
            pa += __shfl_xor(pa, m);
            pb += __shfl_xor(pb, m);
        }
        if (j == 0) {
            ws[AIP_OFF + 2 * n + half] = pa;
            ws[AJP_OFF + 2 * n + half] = pb;
        }
    }
}

// K2: edge pass (R12-proven, unchanged). XCD-swizzled: bid = q*NCHUNK + chunk.
__global__ __launch_bounds__(ETH, 8)
void k_edge(const int* __restrict__ ei, const float* __restrict__ ea,
            const float* __restrict__ att, float* __restrict__ ws, int E, int CH) {
    const int chunk = blockIdx.x & (NCHUNK - 1), q = blockIdx.x >> 6;
    const int dlo = q * QR;
    int drows = NN - dlo; if (drows > QR) drows = QR;
    __shared__ __align__(16) float Wl[QSLOTS_P];
    __shared__ float ajl[NN], ailq[QR], Mq[QR], llast[QR], mred[64];
    int tid = threadIdx.x;
    const float4 z4 = make_float4(0.f, 0.f, 0.f, 0.f);
    for (int i = tid; i < QSLOTS_P / 4; i += ETH) ((float4*)Wl)[i] = z4;
    for (int i = tid; i < NN; i += ETH)
        ajl[i] = ws[AJP_OFF + 2 * i] + ws[AJP_OFF + 2 * i + 1];
    if (tid < QR) llast[tid] = 0.f;
    __syncthreads();
    if (tid < 64) {
        float m = -1e30f;
        for (int i = tid; i < NN; i += 64) m = fmaxf(m, ajl[i]);
        mred[tid] = m;
    }
    __syncthreads();
    if (tid < 16) mred[tid] = fmaxf(fmaxf(mred[tid], mred[tid + 16]),
                                    fmaxf(mred[tid + 32], mred[tid + 48]));
    __syncthreads();
    if (tid < 4) mred[tid] = fmaxf(fmaxf(mred[tid], mred[tid + 4]),
                                   fmaxf(mred[tid + 8], mred[tid + 12]));
    __syncthreads();
    if (tid == 0) mred[0] = fmaxf(fmaxf(mred[0], mred[1]), fmaxf(mred[2], mred[3]));
    __syncthreads();
    const float ajmax = mred[0];
    if (tid < drows) {
        float a = ws[AIP_OFF + 2 * (dlo + tid)] + ws[AIP_OFF + 2 * (dlo + tid) + 1];
        ailq[tid] = a;
        float M = a + ajmax + 1.0f;       // safe softmax shift (shift-invariant)
        Mq[tid] = (M > 0.f) ? M : NEG * M;
    }
    const float cc = att[2 * 128];
    __syncthreads();

    const int base = chunk * CH;
    int lim = base + CH; if (lim > E) lim = E;
    const bool aligned4 = ((E & 3) == 0);
    for (int e0 = base + tid * 4; e0 < lim; e0 += ETH * 4) {
        int4 sv, dv; float4 eav;
        if (aligned4 && e0 + 3 < lim) {
            sv  = *(const int4*)(ei + e0);
            dv  = *(const int4*)(ei + E + e0);
            eav = *(const float4*)(ea + e0);
        } else {
            int e1 = lim - e0;
            sv.x = (e1 > 0) ? ei[e0]     : 0; dv.x = (e1 > 0) ? ei[E + e0]     : -1; eav.x = (e1 > 0) ? ea[e0]     : 0.f;
            sv.y = (e1 > 1) ? ei[e0 + 1] : 0; dv.y = (e1 > 1) ? ei[E + e0 + 1] : -1; eav.y = (e1 > 1) ? ea[e0 + 1] : 0.f;
            sv.z = (e1 > 2) ? ei[e0 + 2] : 0; dv.z = (e1 > 2) ? ei[E + e0 + 2] : -1; eav.z = (e1 > 2) ? ea[e0 + 2] : 0.f;
            sv.w = (e1 > 3) ? ei[e0 + 3] : 0; dv.w = (e1 > 3) ? ei[E + e0 + 3] : -1; eav.w = (e1 > 3) ? ea[e0 + 3] : 0.f;
        }
#define PROC(SS, DD, EE) do {                                   \
            int d_ = (DD) - dlo;                                \
            if ((unsigned)d_ < (unsigned)drows) {               \
                float t_ = ailq[d_] + ajl[SS] + cc * (EE);      \
                t_ = (t_ > 0.f) ? t_ : NEG * t_;                \
                float ev_ = __expf(t_ - Mq[d_]);                \
                atomicAdd(&Wl[d_ * ROWP + (SS)], ev_);          \
                atomicAdd(&llast[d_], ev_ * (EE));              \
            }                                                   \
        } while (0)
        PROC(sv.x, dv.x, eav.x);
        PROC(sv.y, dv.y, eav.y);
        PROC(sv.z, dv.z, eav.z);
        PROC(sv.w, dv.w, eav.w);
#undef PROC
    }
    __syncthreads();
    float* part = ws + PART_OFF + (size_t)blockIdx.x * SL;
    for (int i = tid; i < QSLOTS_P / 4; i += ETH)
        ((float4*)part)[i] = ((const float4*)Wl)[i];
    if (tid < QR) part[QSLOTS_P + tid] = llast[tid];
}

// K3: chunk-reduce -> wl; y = wl@x; v = y@W; o = v@eu; out = (o + wlast*eu_last)/ssum + bias.
// (v = W_att[n,:]@h with h = x@W, factorized as ((wl@x)@W)@eu — h never exists.)
__global__ __launch_bounds__(ETH)
void k_outD(const float* __restrict__ ws, const float* __restrict__ x,
            const float* __restrict__ w, const float* __restrict__ eu,
            const float* __restrict__ bias, float* __restrict__ out) {
    __shared__ __align__(16) float wl[ROWP];
    __shared__ float red[128];
    __shared__ float sc[2];
    __shared__ float yl[128], vl[128];
    __shared__ __align__(16) float pd[2048];
    const int n = blockIdx.x, tid = threadIdx.x;
    const int q = n / QR, r = n % QR;
    const size_t qbase = PART_OFF + (size_t)q * NCHUNK * SL;

    // step 1: W row n = float4 sum over 64 chunks, 8-way chunk-group split
    {
        const int lane = tid & 63, cg = tid >> 6;
        const int s4 = lane * 4;
        float4 acc = make_float4(0.f, 0.f, 0.f, 0.f);
        if (s4 < ROWP) {
            const float* p = ws + qbase + (size_t)(cg * 8) * SL + (size_t)r * ROWP + s4;
#pragma unroll
            for (int ch = 0; ch < 8; ++ch)
                acc = f4add(acc, *(const float4*)(p + (size_t)ch * SL));
        }
        ((float4*)pd)[tid] = acc;
    }
    if (tid < 64) red[tid] = ws[qbase + (size_t)tid * SL + QSLOTS_P + r];
    __syncthreads();
    if (tid < 256) ((float4*)pd)[tid] = f4add(((float4*)pd)[tid], ((float4*)pd)[tid + 256]);
    if (tid < 32) red[tid] += red[tid + 32];
    __syncthreads();
    if (tid < 128) ((float4*)pd)[tid] = f4add(((float4*)pd)[tid], ((float4*)pd)[tid + 128]);
    if (tid < 16) red[tid] += red[tid + 16];
    __syncthreads();
    if (tid < 64) {
        float4 v = f4add(((float4*)pd)[tid], ((float4*)pd)[tid + 64]);
        if (tid * 4 < ROWP) ((float4*)wl)[tid] = v;
    }
    if (tid < 8) red[tid] += red[tid + 8];
    __syncthreads();
    if (tid == 0) {
        float wv = 0.f;
#pragma unroll
        for (int i = 0; i < 8; ++i) wv += red[i];
        sc[0] = wv;                                  // wlast_n
    }
    __syncthreads();
    // ssum = rowsum of wl (pads 177..179 are zero)
    if (tid < 128) red[tid] = wl[tid] + ((tid + 128 < NN) ? wl[tid + 128] : 0.f);
    __syncthreads();
    for (int off = 64; off > 0; off >>= 1) {
        if (tid < off) red[tid] += red[tid + off];
        __syncthreads();
    }
    if (tid == 0) sc[1] = red[0];
    __syncthreads();

    const int c = tid & 127, g = tid >> 7;           // g 0..3

    // step 2: y[c] = sum_s wl[s]*x[s][c]  (4-way s-split; x coalesced, L2-hot)
    {
        float acc = 0.f;
        int s0 = g * 45, s1 = s0 + 45; if (s1 > NN) s1 = NN;
        for (int s = s0; s < s1; ++s) acc += wl[s] * x[s * 128 + c];
        pd[tid] = acc;
    }
    __syncthreads();
    if (tid < 128) yl[tid] = (pd[tid] + pd[128 + tid]) + (pd[256 + tid] + pd[384 + tid]);
    __syncthreads();

    // step 3: v[c] = sum_k y[k]*W[k][c]  (4-way k-split)
    {
        float acc = 0.f;
        const float* wp = w + (size_t)(g * 32) * 128 + c;
#pragma unroll 8
        for (int k = 0; k < 32; ++k) acc += yl[g * 32 + k] * wp[(size_t)k * 128];
        pd[tid] = acc;
    }
    __syncthreads();
    if (tid < 128) vl[tid] = (pd[tid] + pd[128 + tid]) + (pd[256 + tid] + pd[384 + tid]);
    __syncthreads();

    // step 4: o[c] = sum_k v[k]*eu[k][c]; out = (o + wlast*eu[128][c]) / ssum + bias[c]
    {
        float acc = 0.f;
        const float* ep = eu + (size_t)(g * 32) * 128 + c;
#pragma unroll 8
        for (int k = 0; k < 32; ++k) acc += vl[g * 32 + k] * ep[(size_t)k * 128];
        pd[tid] = acc;
    }
    __syncthreads();
    if (tid < 128) {
        float dot = (pd[tid] + pd[128 + tid]) + (pd[256 + tid] + pd[384 + tid]);
        out[n * 128 + tid] = (dot + sc[0] * eu[128 * 128 + tid]) / (sc[1] + 1e-16f) + bias[tid];
    }
}

extern "C" void kernel_launch(void* const* d_in, const int* in_sizes, int n_in,
                              void* d_out, int out_size, void* d_ws, size_t ws_size,
                              hipStream_t stream) {
    const float* x     = (const float*)d_in[0];
    const float* eattr = (const float*)d_in[1];
    const float* w     = (const float*)d_in[2];
    const float* att   = (const float*)d_in[3];
    const float* eu    = (const float*)d_in[4];
    const float* bias  = (const float*)d_in[5];
    const int*   ei    = (const int*)d_in[6];
    int E = in_sizes[6] / 2;
    int CH = (((E + NCHUNK - 1) / NCHUNK) + 3) & ~3;
    float* ws = (float*)d_ws;

    k_nodeA<<<dim3(NN, 2), 256, 0, stream>>>(x, w, att, ws);
    k_edge<<<EBLOCKS, ETH, 0, stream>>>(ei, eattr, att, ws, E, CH);
    k_outD<<<NN, ETH, 0, stream>>>(ws, x, w, eu, bias, (float*)d_out);
}